// Round 12
// baseline (170.210 us; speedup 1.0000x reference)
//
#include <hip/hip_runtime.h>
#include <hip/hip_bf16.h>

#define DD 96
#define CB_BITS 6
#define CB_SIZE 64             // nodes per bin
#define CB_MAXBINS 1024        // supports N <= 65536
#define CBE 2048               // edges per coarse_bin block
#define BIN_CAP 2048           // padded estage slot per bin (mean ~1023 here)
#define AGG_STRIDE 104         // LDS agg row stride in shorts (208 B: 2-way banks)

typedef __attribute__((ext_vector_type(8))) short short8;
typedef __attribute__((ext_vector_type(4))) float floatx4;

__device__ __forceinline__ int load_idx(const void* eidx, int isI64, int pos) {
    return isI64 ? (int)((const long long*)eidx)[pos] : ((const int*)eidx)[pos];
}

__device__ __forceinline__ unsigned int b16(float f) {   // fp32 -> bf16 (RNE)
    unsigned int u = __float_as_uint(f);
    return (u + 0x7fffu + ((u >> 16) & 1u)) >> 16;
}
__device__ __forceinline__ unsigned int pack2(float lo, float hi) {
    return b16(lo) | (b16(hi) << 16);
}

// ================= 1) prep: flag + binCursor init + pack W1/W2 + convert x ==
__global__ __launch_bounds__(256) void prep_kernel(
    const float* __restrict__ x,
    const float* __restrict__ W1_rel, const float* __restrict__ W1_root,
    const float* __restrict__ W2_rel, const float* __restrict__ W2_root,
    const unsigned long long* __restrict__ idx64,
    int* __restrict__ flag, int* __restrict__ binCursor,
    unsigned short* __restrict__ xb,
    uint4* __restrict__ wpack1, uint4* __restrict__ wpack2,
    long long nelem, unsigned long long nmax, int nbins) {
    const int b = blockIdx.x;
    const int tid = threadIdx.x;
    if (b == 0) {
        __shared__ int bad;
        if (tid == 0) bad = 0;
        __syncthreads();
        unsigned long long v = idx64[tid];
        if (v >= nmax) bad = 1;
        __syncthreads();
        if (tid == 0) *flag = bad ? 0 : 1;  // 1 => int64 layout
        for (int i = tid; i < nbins; i += 256) binCursor[i] = i * BIN_CAP;
        return;
    }
    if (b <= 18) {  // 18*256 = 4608 = 2 layers * 36 frags * 64 lanes
        int t = (b - 1) * 256 + tid;
        int layer = t / 2304;
        int tt = t - layer * 2304;
        const float* Wr = layer ? W2_rel : W1_rel;
        const float* Wo = layer ? W2_root : W1_root;
        uint4* wp = layer ? wpack2 : wpack1;
        int f = tt >> 6, lane = tt & 63;
        int kt = f / 6, nt = f % 6;
        int n = nt * 16 + (lane & 15);
        int kbase = kt * 32 + (lane >> 4) * 8;
        float v[8];
        #pragma unroll
        for (int j = 0; j < 8; ++j) {
            int k = kbase + j;
            v[j] = (k < DD) ? Wr[(size_t)k * DD + n]
                            : Wo[(size_t)(k - DD) * DD + n];
        }
        uint4 o;
        o.x = pack2(v[0], v[1]); o.y = pack2(v[2], v[3]);
        o.z = pack2(v[4], v[5]); o.w = pack2(v[6], v[7]);
        wp[tt] = o;
        return;
    }
    long long i = ((long long)(b - 19) * 256 + tid) * 8;
    if (i + 8 > nelem) return;
    float4 f0 = ((const float4*)(x + i))[0];
    float4 f1 = ((const float4*)(x + i))[1];
    uint4 o;
    o.x = pack2(f0.x, f0.y); o.y = pack2(f0.z, f0.w);
    o.z = pack2(f1.x, f1.y); o.w = pack2(f1.z, f1.w);
    *((uint4*)(xb + i)) = o;
}

// ================= 2) coarse binning into padded per-bin slots =============
// Edges register-cached (8/thread). estage entry packed: (dst<<16)|src
// (valid: N <= 65536). bin = u>>22, dst_local = (u>>16)&63, src = u&0xffff.
__global__ __launch_bounds__(256) void coarse_bin_kernel(
    const void* __restrict__ eidx, const int* __restrict__ flag,
    int* __restrict__ binCursor, unsigned int* __restrict__ estage,
    int E, int n, int nbins) {
    __shared__ int cnt[CB_MAXBINS];
    __shared__ int pref[CB_MAXBINS];
    __shared__ int cur[CB_MAXBINS];
    __shared__ int gbase[CB_MAXBINS];
    __shared__ unsigned int ebuf[CBE];
    __shared__ int tot_sh;
    const int tid = threadIdx.x;
    #pragma unroll
    for (int i = 0; i < 4; ++i) cnt[tid + i * 256] = 0;
    __syncthreads();
    const int base = blockIdx.x * CBE;
    const int isI64 = *flag;
    int sr[8], dr[8];
    #pragma unroll
    for (int i = 0; i < 8; ++i) {
        int e = base + tid + i * 256;
        sr[i] = -1; dr[i] = -1;
        if (e < E) {
            int s = load_idx(eidx, isI64, e);
            int d = load_idx(eidx, isI64, E + e);
            if ((unsigned)s < (unsigned)n && (unsigned)d < (unsigned)n) {
                sr[i] = s; dr[i] = d;
                atomicAdd(&cnt[d >> CB_BITS], 1);
            }
        }
    }
    __syncthreads();
    {   // scan 1024 counters, 4 per thread
        int a[4], ps = 0;
        #pragma unroll
        for (int j = 0; j < 4; ++j) { a[j] = cnt[4 * tid + j]; ps += a[j]; }
        gbase[tid] = ps;
        __syncthreads();
        int v = ps;
        for (int off = 1; off < 256; off <<= 1) {
            int o = (tid >= off) ? gbase[tid - off] : 0;
            __syncthreads();
            v += o;
            gbase[tid] = v;
            __syncthreads();
        }
        int run = v - ps;
        #pragma unroll
        for (int j = 0; j < 4; ++j) {
            pref[4 * tid + j] = run;
            cur[4 * tid + j] = run;
            run += a[j];
        }
        if (tid == 255) tot_sh = v;
    }
    __syncthreads();
    const int tot = tot_sh;
    #pragma unroll
    for (int i = 0; i < 8; ++i) {
        if (dr[i] >= 0) {
            int r = atomicAdd(&cur[dr[i] >> CB_BITS], 1);
            ebuf[r] = ((unsigned)dr[i] << 16) | (unsigned)sr[i];
        }
    }
    __syncthreads();
    for (int i = tid; i < nbins; i += 256) {
        int c = cnt[i];
        gbase[i] = c ? atomicAdd(&binCursor[i], c) : 0;
    }
    __syncthreads();
    for (int k = tid; k < tot; k += 256) {
        unsigned int u = ebuf[k];
        int bin = (int)(u >> 22);
        int g = gbase[bin] + (k - pref[bin]);
        if (g < (bin + 1) * BIN_CAP) estage[g] = u;  // overflow/replay guard
    }
}

__device__ __forceinline__ void acc8(float* a, uint4 w) {
    a[0] += __uint_as_float(w.x << 16); a[1] += __uint_as_float(w.x & 0xffff0000u);
    a[2] += __uint_as_float(w.y << 16); a[3] += __uint_as_float(w.y & 0xffff0000u);
    a[4] += __uint_as_float(w.z << 16); a[5] += __uint_as_float(w.z & 0xffff0000u);
    a[6] += __uint_as_float(w.w << 16); a[7] += __uint_as_float(w.w & 0xffff0000u);
}

// ================= 3/4) fused layer: bucket + gather(LDS) + MFMA ===========
// One 256-thread block per 64-node bin. Phase A: single-pass bucket from
// register-cached packed edges. Phase B: gather feat rows into agg_l (bf16,
// fp32 accumulate; stride 104 shorts => 2-way banks = free). Phase C: 4 waves
// MFMA [agg_l | feat_rows] @ wpack + bias -> outf/outb (R7 4-wave mapping).
__global__ __launch_bounds__(256) void layer_kernel(
    const unsigned int* __restrict__ estage, const int* __restrict__ binCursor,
    const unsigned short* __restrict__ feat, const uint4* __restrict__ wpack,
    const float* __restrict__ bias, float* __restrict__ outf,
    unsigned short* __restrict__ outb, int n, int do_relu) {
    __shared__ int cnt[CB_SIZE];
    __shared__ int stl[CB_SIZE];
    __shared__ int cur[CB_SIZE];
    __shared__ int pref[CB_SIZE];
    __shared__ int ssrc_l[BIN_CAP];
    __shared__ unsigned short agg_l[CB_SIZE * AGG_STRIDE];
    const int b = blockIdx.x;
    const int tid = threadIdx.x;
    const unsigned int* ebin = estage + (size_t)b * BIN_CAP;
    int tot = binCursor[b] - b * BIN_CAP;
    tot = (tot < 0) ? 0 : (tot > BIN_CAP ? BIN_CAP : tot);
    if (tid < CB_SIZE) cnt[tid] = 0;
    __syncthreads();
    unsigned int er[8];
    #pragma unroll
    for (int i = 0; i < 8; ++i) {
        int k = tid + i * 256;
        er[i] = 0xffffffffu;
        if (k < tot) {
            unsigned int u = ebin[k];
            er[i] = u;
            atomicAdd(&cnt[(u >> 16) & (CB_SIZE - 1)], 1);
        }
    }
    __syncthreads();
    {
        int v = (tid < CB_SIZE) ? cnt[tid] : 0;
        if (tid < CB_SIZE) pref[tid] = v;
        __syncthreads();
        for (int off = 1; off < CB_SIZE; off <<= 1) {
            int o = (tid < CB_SIZE && tid >= off) ? pref[tid - off] : 0;
            __syncthreads();
            if (tid < CB_SIZE) { v += o; pref[tid] = v; }
            __syncthreads();
        }
        if (tid < CB_SIZE) {
            int st = v - cnt[tid];
            stl[tid] = st;
            cur[tid] = st;
        }
    }
    __syncthreads();
    #pragma unroll
    for (int i = 0; i < 8; ++i) {
        if (er[i] != 0xffffffffu) {
            int pos = atomicAdd(&cur[(er[i] >> 16) & (CB_SIZE - 1)], 1);
            ssrc_l[pos] = (int)(er[i] & 0xffffu);
        }
    }
    __syncthreads();
    // Phase B: gather into agg_l. 768 (node_loc, chunk) pairs, 3 iters.
    #pragma unroll
    for (int it = 0; it < 3; ++it) {
        int p = it * 256 + tid;
        int nl = p / 12, c = p % 12;
        int node = (b << CB_BITS) + nl;
        float accA[8] = {0,0,0,0,0,0,0,0};
        float accB[8] = {0,0,0,0,0,0,0,0};
        if (node < n) {
            int st = stl[nl], en = st + cnt[nl];
            int j = st;
            for (; j + 4 <= en; j += 4) {
                int s0 = ssrc_l[j + 0], s1 = ssrc_l[j + 1];
                int s2 = ssrc_l[j + 2], s3 = ssrc_l[j + 3];
                uint4 w0 = ((const uint4*)(feat + (size_t)s0 * DD))[c];
                uint4 w1 = ((const uint4*)(feat + (size_t)s1 * DD))[c];
                uint4 w2 = ((const uint4*)(feat + (size_t)s2 * DD))[c];
                uint4 w3 = ((const uint4*)(feat + (size_t)s3 * DD))[c];
                acc8(accA, w0); acc8(accB, w1); acc8(accA, w2); acc8(accB, w3);
            }
            for (; j < en; ++j) {
                uint4 w = ((const uint4*)(feat + (size_t)ssrc_l[j] * DD))[c];
                acc8(accA, w);
            }
        }
        uint4 o;
        o.x = pack2(accA[0] + accB[0], accA[1] + accB[1]);
        o.y = pack2(accA[2] + accB[2], accA[3] + accB[3]);
        o.z = pack2(accA[4] + accB[4], accA[5] + accB[5]);
        o.w = pack2(accA[6] + accB[6], accA[7] + accB[7]);
        *((uint4*)&agg_l[nl * AGG_STRIDE + c * 8]) = o;
    }
    __syncthreads();
    // Phase C: MFMA. wave w: N-half p = w>>1, mtiles {w&1, (w&1)+2}.
    {
        const int lane = tid & 63;
        const int w = tid >> 6;
        const int p = w >> 1;
        const int sub = w & 1;
        const int m16 = lane & 15;
        const int quad = lane >> 4;
        const int rowbase = b << CB_BITS;

        short8 bfrag[6][3];
        #pragma unroll
        for (int kt = 0; kt < 6; ++kt)
            #pragma unroll
            for (int ntl = 0; ntl < 3; ++ntl) {
                uint4 u = wpack[(kt * 6 + (p * 3 + ntl)) * 64 + lane];
                bfrag[kt][ntl] = *(short8*)&u;
            }

        floatx4 acc[2][3];
        #pragma unroll
        for (int mi = 0; mi < 2; ++mi)
            #pragma unroll
            for (int ntl = 0; ntl < 3; ++ntl)
                acc[mi][ntl] = (floatx4){0.f, 0.f, 0.f, 0.f};

        #pragma unroll
        for (int kt = 0; kt < 6; ++kt) {
            short8 afrag[2];
            #pragma unroll
            for (int mi = 0; mi < 2; ++mi) {
                const int mt = sub + mi * 2;
                const int mrow = mt * 16 + m16;
                if (kt < 3) {
                    afrag[mi] = *(const short8*)
                        &agg_l[mrow * AGG_STRIDE + kt * 32 + quad * 8];
                } else {
                    int row = rowbase + mrow;
                    int r = (row < n) ? row : 0;
                    afrag[mi] = *(const short8*)
                        (feat + (size_t)r * DD + (kt - 3) * 32 + quad * 8);
                }
            }
            #pragma unroll
            for (int ntl = 0; ntl < 3; ++ntl) {
                acc[0][ntl] = __builtin_amdgcn_mfma_f32_16x16x32_bf16(
                    afrag[0], bfrag[kt][ntl], acc[0][ntl], 0, 0, 0);
                acc[1][ntl] = __builtin_amdgcn_mfma_f32_16x16x32_bf16(
                    afrag[1], bfrag[kt][ntl], acc[1][ntl], 0, 0, 0);
            }
        }

        // C layout: col = lane&15, row-in-tile = quad*4 + reg
        #pragma unroll
        for (int ntl = 0; ntl < 3; ++ntl) {
            const int col = (p * 3 + ntl) * 16 + m16;
            const float bv = bias[col];
            #pragma unroll
            for (int mi = 0; mi < 2; ++mi) {
                const int mt = sub + mi * 2;
                #pragma unroll
                for (int reg = 0; reg < 4; ++reg) {
                    int row = rowbase + mt * 16 + quad * 4 + reg;
                    if (row < n) {
                        float v = acc[mi][ntl][reg] + bv;
                        if (do_relu) v = fmaxf(v, 0.f);
                        if (outf) outf[(size_t)row * DD + col] = v;
                        if (outb) outb[(size_t)row * DD + col] =
                            (unsigned short)b16(v);
                    }
                }
            }
        }
    }
}

// ================= fallbacks (fp32 path, ws too small / N too big) =========
__global__ void detect_idx_kernel(const unsigned long long* __restrict__ idx,
                                  int* __restrict__ flag,
                                  unsigned long long nmax) {
    __shared__ int bad;
    if (threadIdx.x == 0) bad = 0;
    __syncthreads();
    unsigned long long v = idx[threadIdx.x];
    if (v >= nmax) bad = 1;
    __syncthreads();
    if (threadIdx.x == 0) *flag = bad ? 0 : 1;
}

__global__ __launch_bounds__(256) void scatter_add_kernel(
    const float* __restrict__ feat, const void* __restrict__ eidx,
    const int* __restrict__ flag, float* __restrict__ agg,
    int E, int n) {
    long long t = (long long)blockIdx.x * 256 + threadIdx.x;
    if (t >= (long long)E * 24) return;
    int e = (int)(t / 24);
    int c = (int)(t % 24);
    int isI64 = *flag;
    int s = load_idx(eidx, isI64, e);
    int d = load_idx(eidx, isI64, E + e);
    if ((unsigned)s >= (unsigned)n || (unsigned)d >= (unsigned)n) return;
    const float4 v = ((const float4*)(feat + (size_t)s * DD))[c];
    float* o = agg + (size_t)d * DD + (size_t)c * 4;
    atomicAdd(o + 0, v.x);
    atomicAdd(o + 1, v.y);
    atomicAdd(o + 2, v.z);
    atomicAdd(o + 3, v.w);
}

__global__ __launch_bounds__(256, 4) void linear64_kernel(
    const float* __restrict__ A, const float* __restrict__ X,
    const float* __restrict__ Wrel, const float* __restrict__ bias,
    const float* __restrict__ Wroot, float* __restrict__ out,
    int n, int do_relu) {
    __shared__ float wlds[DD * DD];
    const int lane = threadIdx.x & 63;
    const int q = threadIdx.x >> 6;
    const int j0 = q * 24;
    const int node = blockIdx.x * 64 + lane;
    const bool act = (node < n);
    const int r = act ? node : 0;
    float acc[24];
    {
        const float4* bq = (const float4*)(bias + j0);
        #pragma unroll
        for (int jj = 0; jj < 6; ++jj) {
            float4 b = bq[jj];
            acc[jj*4+0] = b.x; acc[jj*4+1] = b.y;
            acc[jj*4+2] = b.z; acc[jj*4+3] = b.w;
        }
    }
    const float* srcs[2] = {A, X};
    const float* mats[2] = {Wrel, Wroot};
    for (int phase = 0; phase < 2; ++phase) {
        {
            const float4* wg = (const float4*)mats[phase];
            float4* wl = (float4*)wlds;
            #pragma unroll
            for (int i = 0; i < 9; ++i)
                wl[threadIdx.x + i * 256] = wg[threadIdx.x + i * 256];
        }
        __syncthreads();
        const float* row = srcs[phase] + (size_t)r * DD;
        for (int kk = 0; kk < DD; kk += 4) {
            float4 a4 = *(const float4*)(row + kk);
            const float av[4] = {a4.x, a4.y, a4.z, a4.w};
            #pragma unroll
            for (int u = 0; u < 4; ++u) {
                const float4* wrow = (const float4*)(&wlds[(kk + u) * DD + j0]);
                const float ka = av[u];
                #pragma unroll
                for (int jj = 0; jj < 6; ++jj) {
                    float4 ww = wrow[jj];
                    acc[jj*4+0] = fmaf(ka, ww.x, acc[jj*4+0]);
                    acc[jj*4+1] = fmaf(ka, ww.y, acc[jj*4+1]);
                    acc[jj*4+2] = fmaf(ka, ww.z, acc[jj*4+2]);
                    acc[jj*4+3] = fmaf(ka, ww.w, acc[jj*4+3]);
                }
            }
        }
        __syncthreads();
    }
    if (act) {
        float4* o = (float4*)(out + (size_t)node * DD + j0);
        #pragma unroll
        for (int jj = 0; jj < 6; ++jj) {
            float4 v = make_float4(acc[jj*4+0], acc[jj*4+1],
                                   acc[jj*4+2], acc[jj*4+3]);
            if (do_relu) {
                v.x = fmaxf(v.x, 0.f); v.y = fmaxf(v.y, 0.f);
                v.z = fmaxf(v.z, 0.f); v.w = fmaxf(v.w, 0.f);
            }
            o[jj] = v;
        }
    }
}

__global__ __launch_bounds__(256) void linear_kernel(
    const float* __restrict__ A, const float* __restrict__ X,
    const float* __restrict__ Wrel, const float* __restrict__ bias,
    const float* __restrict__ Wroot, float* __restrict__ out,
    int n, int do_relu) {
    __shared__ float wlds[DD * DD];
    const int lane = threadIdx.x & 63;
    const int q = threadIdx.x >> 6;
    const int j0 = q * 24;
    const int m0 = blockIdx.x * 128 + lane;
    const int m1 = m0 + 64;
    const bool act0 = (m0 < n), act1 = (m1 < n);
    const int r0 = act0 ? m0 : 0;
    const int r1 = act1 ? m1 : 0;
    float acc0[24], acc1[24];
    {
        const float4* bq = (const float4*)(bias + j0);
        #pragma unroll
        for (int jj = 0; jj < 6; ++jj) {
            float4 b = bq[jj];
            acc0[jj*4+0] = b.x; acc0[jj*4+1] = b.y;
            acc0[jj*4+2] = b.z; acc0[jj*4+3] = b.w;
            acc1[jj*4+0] = b.x; acc1[jj*4+1] = b.y;
            acc1[jj*4+2] = b.z; acc1[jj*4+3] = b.w;
        }
    }
    const float* srcs[2] = {A, X};
    const float* mats[2] = {Wrel, Wroot};
    for (int phase = 0; phase < 2; ++phase) {
        {
            const float4* wg = (const float4*)mats[phase];
            float4* wl = (float4*)wlds;
            #pragma unroll
            for (int i = 0; i < 9; ++i)
                wl[threadIdx.x + i * 256] = wg[threadIdx.x + i * 256];
        }
        __syncthreads();
        const float* row0 = srcs[phase] + (size_t)r0 * DD;
        const float* row1 = srcs[phase] + (size_t)r1 * DD;
        for (int kk = 0; kk < DD; kk += 4) {
            float4 a0 = *(const float4*)(row0 + kk);
            float4 a1 = *(const float4*)(row1 + kk);
            const float av0[4] = {a0.x, a0.y, a0.z, a0.w};
            const float av1[4] = {a1.x, a1.y, a1.z, a1.w};
            #pragma unroll
            for (int u = 0; u < 4; ++u) {
                const float4* wrow = (const float4*)(&wlds[(kk + u) * DD + j0]);
                const float k0 = av0[u], k1 = av1[u];
                #pragma unroll
                for (int jj = 0; jj < 6; ++jj) {
                    float4 ww = wrow[jj];
                    acc0[jj*4+0] = fmaf(k0, ww.x, acc0[jj*4+0]);
                    acc0[jj*4+1] = fmaf(k0, ww.y, acc0[jj*4+1]);
                    acc0[jj*4+2] = fmaf(k0, ww.z, acc0[jj*4+2]);
                    acc0[jj*4+3] = fmaf(k0, ww.w, acc0[jj*4+3]);
                    acc1[jj*4+0] = fmaf(k1, ww.x, acc1[jj*4+0]);
                    acc1[jj*4+1] = fmaf(k1, ww.y, acc1[jj*4+1]);
                    acc1[jj*4+2] = fmaf(k1, ww.z, acc1[jj*4+2]);
                    acc1[jj*4+3] = fmaf(k1, ww.w, acc1[jj*4+3]);
                }
            }
        }
        __syncthreads();
    }
    if (act0) {
        float4* o = (float4*)(out + (size_t)m0 * DD + j0);
        #pragma unroll
        for (int jj = 0; jj < 6; ++jj) {
            float4 v = make_float4(acc0[jj*4+0], acc0[jj*4+1],
                                   acc0[jj*4+2], acc0[jj*4+3]);
            if (do_relu) {
                v.x = fmaxf(v.x, 0.f); v.y = fmaxf(v.y, 0.f);
                v.z = fmaxf(v.z, 0.f); v.w = fmaxf(v.w, 0.f);
            }
            o[jj] = v;
        }
    }
    if (act1) {
        float4* o = (float4*)(out + (size_t)m1 * DD + j0);
        #pragma unroll
        for (int jj = 0; jj < 6; ++jj) {
            float4 v = make_float4(acc1[jj*4+0], acc1[jj*4+1],
                                   acc1[jj*4+2], acc1[jj*4+3]);
            if (do_relu) {
                v.x = fmaxf(v.x, 0.f); v.y = fmaxf(v.y, 0.f);
                v.z = fmaxf(v.z, 0.f); v.w = fmaxf(v.w, 0.f);
            }
            o[jj] = v;
        }
    }
}

extern "C" void kernel_launch(void* const* d_in, const int* in_sizes, int n_in,
                              void* d_out, int out_size, void* d_ws, size_t ws_size,
                              hipStream_t stream) {
    const float* x      = (const float*)d_in[0];
    const void*  eidx   = d_in[1];
    const float* W1_rel = (const float*)d_in[2];
    const float* b1     = (const float*)d_in[3];
    const float* W1_root= (const float*)d_in[4];
    const float* W2_rel = (const float*)d_in[5];
    const float* b2     = (const float*)d_in[6];
    const float* W2_root= (const float*)d_in[7];
    float* out = (float*)d_out;

    const int N = in_sizes[0] / DD;   // 50000
    const int E = in_sizes[1] / 2;    // 800000
    const int nbins = (N + CB_SIZE - 1) >> CB_BITS;
    const long long nelem = (long long)N * DD;
    char* base = (char*)d_ws;

    size_t off = 0;
    auto alloc = [&](size_t bytes) {
        size_t o = off; off = (off + bytes + 255) & ~(size_t)255; return base + o; };
    int*   flag      = (int*)  alloc(256);
    int*   binCursor = (int*)  alloc((size_t)(CB_MAXBINS + 1) * 4);
    unsigned int* estage = (unsigned int*)alloc((size_t)nbins * BIN_CAP * 4);
    unsigned short* xb   = (unsigned short*)alloc((size_t)nelem * 2);
    unsigned short* hb   = (unsigned short*)alloc((size_t)nelem * 2);
    uint4* wpack1    = (uint4*)alloc(36 * 64 * 16);
    uint4* wpack2    = (uint4*)alloc(36 * 64 * 16);
    // need: ws fits; nbins in range; N fits 16-bit src packing; headroom on
    // mean edges/bin <= 2/3 of BIN_CAP (uniform-ish dst assumption)
    const bool mfma_ok = (off <= ws_size) && (nbins <= CB_MAXBINS) &&
                         (nbins > 0) && (N <= 65536) &&
                         (3LL * (E / nbins) <= 2LL * BIN_CAP);

    size_t offB = 512;
    auto allocB = [&](size_t bytes) {
        size_t o = offB; offB = (offB + bytes + 255) & ~(size_t)255; return base + o; };
    float* agg = (float*)allocB((size_t)nelem * 4);
    const bool fb_ok = (offB <= ws_size);

    if (mfma_ok) {
        const int conv_blocks = (int)((nelem / 8 + 255) / 256);
        prep_kernel<<<19 + conv_blocks, 256, 0, stream>>>(
            x, W1_rel, W1_root, W2_rel, W2_root,
            (const unsigned long long*)eidx, flag, binCursor,
            xb, wpack1, wpack2, nelem, (unsigned long long)N, nbins);
        coarse_bin_kernel<<<(E + CBE - 1) / CBE, 256, 0, stream>>>(
            eidx, flag, binCursor, estage, E, N, nbins);
        layer_kernel<<<nbins, 256, 0, stream>>>(
            estage, binCursor, xb, wpack1, b1,
            (float*)nullptr, hb, N, 1);
        layer_kernel<<<nbins, 256, 0, stream>>>(
            estage, binCursor, hb, wpack2, b2,
            out, (unsigned short*)nullptr, N, 0);
    } else if (fb_ok) {
        const int scatter_blocks = (int)(((long long)E * 24 + 255) / 256);
        detect_idx_kernel<<<1, 256, 0, stream>>>(
            (const unsigned long long*)eidx, flag, (unsigned long long)N);
        hipMemsetAsync(agg, 0, (size_t)nelem * 4, stream);
        scatter_add_kernel<<<scatter_blocks, 256, 0, stream>>>(x, eidx, flag, agg, E, N);
        linear64_kernel<<<(N + 63) / 64, 256, 0, stream>>>(
            agg, x, W1_rel, b1, W1_root, out, N, 1);
        hipMemsetAsync(agg, 0, (size_t)nelem * 4, stream);
        scatter_add_kernel<<<scatter_blocks, 256, 0, stream>>>(out, eidx, flag, agg, E, N);
        linear_kernel<<<(N + 127) / 128, 256, 0, stream>>>(
            agg, out, W2_rel, b2, W2_root, out, N, 0);
    }
}